// Round 1
// baseline (1718.610 us; speedup 1.0000x reference)
//
#include <hip/hip_runtime.h>
#include <math.h>

#define NQ 14
#define DIM (1 << NQ)        // 16384
#define NROTS 112
#define NT 4
#define NTH 512
#define APT (DIM / NTH)      // 32 complex amps per thread

// RY on bit p: pairs (i0, i0|1<<p), real rotation
__device__ __forceinline__ void ry_gate(float2* __restrict__ S, int tid, int p,
                                        float c, float s) {
  const int mask = (1 << p) - 1;
#pragma unroll
  for (int it = 0; it < (DIM / 2) / NTH; ++it) {
    int q = tid + it * NTH;                       // pair index, 13 bits
    int i0 = ((q & ~mask) << 1) | (q & mask);     // insert 0 at bit p
    int i1 = i0 | (1 << p);
    float2 a0 = S[i0], a1 = S[i1];
    float2 n0, n1;
    n0.x = c * a0.x - s * a1.x;  n0.y = c * a0.y - s * a1.y;
    n1.x = s * a0.x + c * a1.x;  n1.y = s * a0.y + c * a1.y;
    S[i0] = n0; S[i1] = n1;
  }
}

// CRX: ctrl bit pc must be 1; RX on tgt bit pt. n0 = c*t0 - i*s*t1 ; n1 = -i*s*t0 + c*t1
__device__ __forceinline__ void crx_gate(float2* __restrict__ S, int tid, int pc,
                                         int pt, float c, float s) {
  const int pl = pc < pt ? pc : pt;
  const int ph = pc < pt ? pt : pc;
  const int ml = (1 << pl) - 1, mh = (1 << ph) - 1;
#pragma unroll
  for (int it = 0; it < (DIM / 4) / NTH; ++it) {
    int q = tid + it * NTH;                       // 12 bits
    int u = ((q & ~ml) << 1) | (q & ml);          // insert 0 at pl
    int v = ((u & ~mh) << 1) | (u & mh);          // insert 0 at ph
    int i0 = v | (1 << pc);                       // ctrl=1, tgt=0
    int i1 = i0 | (1 << pt);                      // ctrl=1, tgt=1
    float2 a0 = S[i0], a1 = S[i1];
    float2 n0, n1;
    n0.x = c * a0.x + s * a1.y;  n0.y = c * a0.y - s * a1.x;
    n1.x = s * a0.y + c * a1.x;  n1.y = c * a1.y - s * a0.x;
    S[i0] = n0; S[i1] = n1;
  }
}

// full 112-gate sim14 circuit; CS holds (cos, sin) of theta/2 per gate
__device__ void run_circuit(float2* __restrict__ S, const float2* __restrict__ CS,
                            int tid) {
  int idx = 0;
  for (int layer = 0; layer < 2; ++layer) {
    for (int i = 0; i < 14; ++i) {               // RY wires 0..13
      float2 g = CS[idx]; ry_gate(S, tid, 13 - i, g.x, g.y); ++idx;
      __syncthreads();
    }
    for (int i = 13; i >= 0; --i) {              // CRX ctrl=i tgt=(i+1)%14
      float2 g = CS[idx];
      crx_gate(S, tid, 13 - i, 13 - ((i + 1) % 14), g.x, g.y); ++idx;
      __syncthreads();
    }
    for (int i = 0; i < 14; ++i) {               // RY wires 0..13
      float2 g = CS[idx]; ry_gate(S, tid, 13 - i, g.x, g.y); ++idx;
      __syncthreads();
    }
    {                                            // i=13: ctrl=13 tgt=12
      float2 g = CS[idx]; crx_gate(S, tid, 0, 1, g.x, g.y); ++idx;
      __syncthreads();
    }
    for (int i = 0; i < 13; ++i) {               // ctrl=i tgt=(i-1)%14
      float2 g = CS[idx];
      crx_gate(S, tid, 13 - i, 13 - ((i + 13) % 14), g.x, g.y); ++idx;
      __syncthreads();
    }
  }
}

__global__ __launch_bounds__(NTH) void qts_kernel(
    const float* __restrict__ x, const float* __restrict__ Win,
    const float* __restrict__ bin, const float* __restrict__ mix,
    const float* __restrict__ poly, const float* __restrict__ Wout,
    const float* __restrict__ bout, float* __restrict__ out) {
  extern __shared__ float2 S[];        // DIM state + NROTS cos/sin table
  float2* CS = S + DIM;
  const int tid = threadIdx.x;
  const int b = blockIdx.x;

  float2 res[APT], basev[APT], cur[APT];
#pragma unroll
  for (int i = 0; i < APT; ++i) {
    res[i] = make_float2(0.f, 0.f);
    basev[i] = make_float2(0.f, 0.f);
  }
  float inv = 0.f;

  for (int d = 0; d < 3; ++d) {
#pragma unroll
    for (int i = 0; i < APT; ++i) cur[i] = make_float2(0.f, 0.f);

    for (int t = 0; t < NT; ++t) {
      // compute this (b,t)'s 112 gate angles -> (cos,sin) of theta/2
      if (tid < NROTS) {
        int j = t * NROTS + tid;
        float acc = bin[j];
#pragma unroll
        for (int s4 = 0; s4 < 4; ++s4) acc += x[b * 4 + s4] * Win[s4 * (NT * NROTS) + j];
        float ang = 1.f / (1.f + expf(-acc));    // sigmoid
        float sn, cc;
        sincosf(0.5f * ang, &sn, &cc);
        CS[tid] = make_float2(cc, sn);
      }
      // init state = base
      if (d == 0) {
#pragma unroll
        for (int i = 0; i < APT; ++i) S[tid + NTH * i] = make_float2(0.f, 0.f);
        if (tid == 0) S[0] = make_float2(1.f, 0.f);
      } else {
#pragma unroll
        for (int i = 0; i < APT; ++i)
          S[tid + NTH * i] = make_float2(basev[i].x * inv, basev[i].y * inv);
      }
      __syncthreads();

      run_circuit(S, CS, tid);
      // (run_circuit ends with a barrier)

      float mc = mix[t];
#pragma unroll
      for (int i = 0; i < APT; ++i) {
        float2 v = S[tid + NTH * i];
        cur[i].x = fmaf(mc, v.x, cur[i].x);
        cur[i].y = fmaf(mc, v.y, cur[i].y);
      }
      // no barrier needed: next iter writes only this thread's own S slots / CS
    }

    float pc = poly[d];
#pragma unroll
    for (int i = 0; i < APT; ++i) {
      res[i].x = fmaf(pc, cur[i].x, res[i].x);
      res[i].y = fmaf(pc, cur[i].y, res[i].y);
    }

    if (d < 2) {
      // norm of cur over the whole workgroup
      float part = 0.f;
#pragma unroll
      for (int i = 0; i < APT; ++i)
        part += cur[i].x * cur[i].x + cur[i].y * cur[i].y;
#pragma unroll
      for (int off = 32; off; off >>= 1) part += __shfl_xor(part, off);
      __syncthreads();                 // everyone done reading S
      float* red = (float*)S;
      if ((tid & 63) == 0) red[tid >> 6] = part;
      __syncthreads();
      float tot = 0.f;
#pragma unroll
      for (int w = 0; w < NTH / 64; ++w) tot += red[w];
      inv = 1.f / (sqrtf(tot) + 1e-9f);
#pragma unroll
      for (int i = 0; i < APT; ++i) basev[i] = cur[i];
      __syncthreads();                 // before next degree overwrites S
    }
  }

  // final: expval_z per wire + total norm, from res[] (unnormalized)
  float part[15];
#pragma unroll
  for (int v2 = 0; v2 < 15; ++v2) part[v2] = 0.f;
#pragma unroll
  for (int i = 0; i < APT; ++i) {
    int idx = tid + NTH * i;
    float p = res[i].x * res[i].x + res[i].y * res[i].y;
    part[14] += p;
#pragma unroll
    for (int w = 0; w < 14; ++w) part[w] += ((idx >> (13 - w)) & 1) ? -p : p;
  }
  __syncthreads();                     // S reuse as reduction scratch
  float* red = (float*)S;
#pragma unroll
  for (int v2 = 0; v2 < 15; ++v2) {
    float xv = part[v2];
#pragma unroll
    for (int off = 32; off; off >>= 1) xv += __shfl_xor(xv, off);
    if ((tid & 63) == 0) red[(tid >> 6) * 15 + v2] = xv;
  }
  __syncthreads();
  if (tid < 15) {
    float tot = 0.f;
#pragma unroll
    for (int w = 0; w < NTH / 64; ++w) tot += red[w * 15 + tid];
    red[128 + tid] = tot;
  }
  __syncthreads();
  if (tid < 2) {
    float nrm = sqrtf(red[128 + 14]) + 1e-9f;
    float iv = 1.f / (nrm * nrm);      // expz = S_w / (||res||+eps)^2
    float acc = bout[tid];
#pragma unroll
    for (int w = 0; w < 14; ++w) acc += red[128 + w] * iv * Wout[w * 2 + tid];
    out[b * 2 + tid] = acc;
  }
}

extern "C" void kernel_launch(void* const* d_in, const int* in_sizes, int n_in,
                              void* d_out, int out_size, void* d_ws, size_t ws_size,
                              hipStream_t stream) {
  const float* x    = (const float*)d_in[0];
  const float* Win  = (const float*)d_in[1];
  const float* bin  = (const float*)d_in[2];
  const float* mix  = (const float*)d_in[3];
  const float* poly = (const float*)d_in[4];
  const float* Wout = (const float*)d_in[5];
  const float* bout = (const float*)d_in[6];
  float* out = (float*)d_out;

  size_t shmem = (size_t)DIM * sizeof(float2) + NROTS * sizeof(float2);  // 131968 B
  hipFuncSetAttribute((const void*)qts_kernel,
                      hipFuncAttributeMaxDynamicSharedMemorySize, (int)shmem);
  qts_kernel<<<256, NTH, shmem, stream>>>(x, Win, bin, mix, poly, Wout, bout, out);
}

// Round 2
// 935.441 us; speedup vs baseline: 1.8372x; 1.8372x over previous
//
#include <hip/hip_runtime.h>
#include <math.h>

#define DIM 16384
#define NTH 512

typedef float v2f __attribute__((ext_vector_type(2)));

// wire w <-> bit position (13-w). XOR bank-fold swizzle (bijective, XOR-linear).
__host__ __device__ constexpr int cswz(int i) {
  return i ^ ((i >> 4) & 15) ^ ((i >> 8) & 15) ^ ((i >> 12) & 3);
}

// local wires per pass (local bit b <-> wire LW[p][b])
constexpr int LW[8][5] = {
  {13, 12, 11, 10, 0},   // WA
  {10, 9, 8, 7, 6},      // WB
  {6, 5, 4, 3, 2},       // WC
  {2, 1, 0, 3, 4},       // WD (3,4 pad)
  {12, 13, 0, 1, 2},     // WE
  {2, 3, 4, 5, 6},       // WF
  {6, 7, 8, 9, 10},      // WG
  {10, 11, 12, 13, 9},   // WH (9 pad)
};
// tid bit k -> bit position PMAP[p][k] (permutations chosen so the 6 lane bits
// XOR-fold onto all 4 bank-pair classes -> conflict-floor gathers)
constexpr int PMAP[8][9] = {
  {4, 5, 6, 7, 8, 9, 10, 11, 12},
  {0, 1, 2, 11, 8, 9, 10, 12, 13},
  {0, 1, 2, 3, 4, 5, 6, 12, 13},
  {0, 1, 2, 3, 4, 5, 6, 7, 8},
  {2, 3, 4, 5, 6, 7, 8, 9, 10},
  {0, 1, 2, 3, 4, 5, 6, 12, 13},
  {0, 1, 2, 11, 8, 9, 10, 12, 13},
  {5, 6, 7, 8, 9, 10, 11, 12, 13},
};
constexpr int NG[8] = {9, 8, 8, 3, 9, 8, 8, 3};
// {kind(0=RY,1=CRX), bitA(RY tgt / CRX ctrl), bitB(CRX tgt), cs index (layer-rel)}
constexpr int GATES[8][9][4] = {
  {{0,4,0,0},{0,3,0,10},{0,2,0,11},{0,1,0,12},{0,0,0,13},{1,0,4,14},{1,1,0,15},{1,2,1,16},{1,3,2,17}},
  {{0,4,0,6},{0,3,0,7},{0,2,0,8},{0,1,0,9},{1,1,0,18},{1,2,1,19},{1,3,2,20},{1,4,3,21},{0,0,0,0}},
  {{0,4,0,2},{0,3,0,3},{0,2,0,4},{0,1,0,5},{1,1,0,22},{1,2,1,23},{1,3,2,24},{1,4,3,25},{0,0,0,0}},
  {{0,1,0,1},{1,1,0,26},{1,2,1,27},{0,0,0,0},{0,0,0,0},{0,0,0,0},{0,0,0,0},{0,0,0,0},{0,0,0,0}},
  {{0,2,0,28},{0,3,0,29},{0,4,0,30},{0,0,0,40},{0,1,0,41},{1,1,0,42},{1,2,1,43},{1,3,2,44},{1,4,3,45}},
  {{0,1,0,31},{0,2,0,32},{0,3,0,33},{0,4,0,34},{1,1,0,46},{1,2,1,47},{1,3,2,48},{1,4,3,49},{0,0,0,0}},
  {{0,1,0,35},{0,2,0,36},{0,3,0,37},{0,4,0,38},{1,1,0,50},{1,2,1,51},{1,3,2,52},{1,4,3,53},{0,0,0,0}},
  {{0,1,0,39},{1,1,0,54},{1,2,1,55},{0,0,0,0},{0,0,0,0},{0,0,0,0},{0,0,0,0},{0,0,0,0},{0,0,0,0}},
};

__host__ __device__ constexpr int offcube(int p, int j) {
  int o = 0;
  for (int b = 0; b < 5; ++b)
    if ((j >> b) & 1) o |= 1 << (13 - LW[p][b]);
  return o;
}

// MODE: 0 = gather+gates+scatter, 1 = |0>-init+gates+scatter, 2 = gather+gates (no scatter)
template <int PID, int MODE>
__device__ __forceinline__ void run_pass(v2f* __restrict__ S, const v2f* __restrict__ CS,
                                         int lb, int tid, v2f* __restrict__ a) {
  int base = 0;
#pragma unroll
  for (int k = 0; k < 9; ++k) base |= ((tid >> k) & 1) << PMAP[PID][k];
  const int sb = cswz(base);
  if (MODE == 1) {
#pragma unroll
    for (int j = 0; j < 32; ++j) a[j] = v2f{0.f, 0.f};
    if (tid == 0) a[0] = v2f{1.f, 0.f};
  } else {
#pragma unroll
    for (int j = 0; j < 32; ++j) a[j] = S[sb ^ cswz(offcube(PID, j))];
  }
#pragma unroll
  for (int g = 0; g < NG[PID]; ++g) {
    const v2f cs2 = CS[lb + GATES[PID][g][3]];
    const float c = cs2.x, s = cs2.y;
    if (GATES[PID][g][0] == 0) {
      const int tb = GATES[PID][g][1];
#pragma unroll
      for (int j = 0; j < 32; ++j)
        if (!((j >> tb) & 1)) {
          const int j2 = j | (1 << tb);
          const v2f a0 = a[j], a1 = a[j2];
          a[j]  = c * a0 - s * a1;
          a[j2] = s * a0 + c * a1;
        }
    } else {
      const int bc = GATES[PID][g][1], bt = GATES[PID][g][2];
#pragma unroll
      for (int j = 0; j < 32; ++j)
        if (((j >> bc) & 1) && !((j >> bt) & 1)) {
          const int j2 = j | (1 << bt);
          const v2f t0 = a[j], t1 = a[j2];
          a[j]  = c * t0 + s * v2f{t1.y, -t1.x};
          a[j2] = c * t1 + s * v2f{t0.y, -t0.x};
        }
    }
  }
  if (MODE != 2) {
#pragma unroll
    for (int j = 0; j < 32; ++j) S[sb ^ cswz(offcube(PID, j))] = a[j];
  }
  __syncthreads();
}

// one full 112-gate sim; a[] ends holding the final state in the WH cube mapping
__device__ __forceinline__ void run_sim(v2f* __restrict__ S, const v2f* __restrict__ CS,
                                        int tid, v2f* __restrict__ a,
                                        const v2f* __restrict__ basev, int own_sb,
                                        bool initzero) {
  if (initzero) {
    run_pass<0, 1>(S, CS, 0, tid, a);
  } else {
#pragma unroll
    for (int j = 0; j < 32; ++j) S[own_sb ^ cswz(offcube(7, j))] = basev[j];
    __syncthreads();
    run_pass<0, 0>(S, CS, 0, tid, a);
  }
  run_pass<1, 0>(S, CS, 0, tid, a);
  run_pass<2, 0>(S, CS, 0, tid, a);
  run_pass<3, 0>(S, CS, 0, tid, a);
  run_pass<4, 0>(S, CS, 0, tid, a);
  run_pass<5, 0>(S, CS, 0, tid, a);
  run_pass<6, 0>(S, CS, 0, tid, a);
  run_pass<7, 0>(S, CS, 0, tid, a);
  run_pass<0, 0>(S, CS, 56, tid, a);
  run_pass<1, 0>(S, CS, 56, tid, a);
  run_pass<2, 0>(S, CS, 56, tid, a);
  run_pass<3, 0>(S, CS, 56, tid, a);
  run_pass<4, 0>(S, CS, 56, tid, a);
  run_pass<5, 0>(S, CS, 56, tid, a);
  run_pass<6, 0>(S, CS, 56, tid, a);
  run_pass<7, 2>(S, CS, 56, tid, a);  // final: keep in registers
}

__device__ __forceinline__ float block_sum(float v, int tid, float* red) {
#pragma unroll
  for (int off = 32; off; off >>= 1) v += __shfl_xor(v, off);
  if ((tid & 63) == 0) red[tid >> 6] = v;
  __syncthreads();
  float tot = 0.f;
#pragma unroll
  for (int w = 0; w < 8; ++w) tot += red[w];
  __syncthreads();
  return tot;
}

__global__ __launch_bounds__(NTH, 2) void qts_kernel(
    const float* __restrict__ x, const float* __restrict__ Win,
    const float* __restrict__ bin, const float* __restrict__ mix,
    const float* __restrict__ poly, const float* __restrict__ Wout,
    const float* __restrict__ bout, float* __restrict__ out) {
  extern __shared__ v2f S[];           // DIM state + 448 cos/sin + reduce scratch
  v2f* CSall = S + DIM;
  float* red = (float*)(S + DIM + 448);
  const int tid = threadIdx.x;
  const int b = blockIdx.x;

  // angles for all 4 timesteps at once: theta = sigmoid(x@Win+bin); store (cos,sin)(theta/2)
  if (tid < 448) {
    float z = bin[tid];
    const float x0 = x[b * 4 + 0], x1 = x[b * 4 + 1], x2 = x[b * 4 + 2], x3 = x[b * 4 + 3];
    z += x0 * Win[tid] + x1 * Win[448 + tid] + x2 * Win[896 + tid] + x3 * Win[1344 + tid];
    const float th = 1.f / (1.f + expf(-z));
    float sn, cc;
    sincosf(0.5f * th, &sn, &cc);
    CSall[tid] = v2f{cc, sn};
  }
  __syncthreads();

  int ownbase = 0;
#pragma unroll
  for (int k = 0; k < 9; ++k) ownbase |= ((tid >> k) & 1) << PMAP[7][k];
  const int own_sb = cswz(ownbase);

  const float mixv[4] = {mix[0], mix[1], mix[2], mix[3]};
  const float p0 = poly[0], p1 = poly[1], p2 = poly[2];

  v2f a[32], acc[32], basev[32];
  float alpha;

  // ---- degree 0 (base = |0>) ----
#pragma unroll
  for (int j = 0; j < 32; ++j) acc[j] = v2f{0.f, 0.f};
  for (int t = 0; t < 4; ++t) {
    run_sim(S, CSall + t * 112, tid, a, basev, own_sb, true);
    const float mc = mixv[t];
#pragma unroll
    for (int j = 0; j < 32; ++j) acc[j] += mc * a[j];
  }
  {
    float part = 0.f;
#pragma unroll
    for (int j = 0; j < 32; ++j) part += acc[j].x * acc[j].x + acc[j].y * acc[j].y;
    const float tot = block_sum(part, tid, red);
    const float nu = sqrtf(tot) + 1e-9f;
    const float inv = 1.f / nu;
    alpha = p0 * nu;                   // res-so-far == alpha * basev
#pragma unroll
    for (int j = 0; j < 32; ++j) { basev[j] = inv * acc[j]; acc[j] = v2f{0.f, 0.f}; }
  }

  // ---- degree 1 ----
  for (int t = 0; t < 4; ++t) {
    run_sim(S, CSall + t * 112, tid, a, basev, own_sb, false);
    const float mc = mixv[t];
#pragma unroll
    for (int j = 0; j < 32; ++j) acc[j] += mc * a[j];
  }
  {
    float part = 0.f;
#pragma unroll
    for (int j = 0; j < 32; ++j) part += acc[j].x * acc[j].x + acc[j].y * acc[j].y;
    const float tot = block_sum(part, tid, red);
    const float nu = sqrtf(tot) + 1e-9f;
    const float inv = 1.f / nu;
#pragma unroll
    for (int j = 0; j < 32; ++j) {
      const v2f tmp = acc[j];
      acc[j] = alpha * basev[j] + p1 * tmp;  // acc becomes res accumulator
      basev[j] = inv * tmp;
    }
  }

  // ---- degree 2 (accumulate straight into res) ----
  for (int t = 0; t < 4; ++t) {
    run_sim(S, CSall + t * 112, tid, a, basev, own_sb, false);
    const float mc = p2 * mixv[t];
#pragma unroll
    for (int j = 0; j < 32; ++j) acc[j] += mc * a[j];
  }

  // ---- expz per wire + total norm from res (= acc), then tiny GEMV ----
  float part[15];
#pragma unroll
  for (int v = 0; v < 15; ++v) part[v] = 0.f;
#pragma unroll
  for (int j = 0; j < 32; ++j) {
    const int idx = ownbase | offcube(7, j);
    const float p = acc[j].x * acc[j].x + acc[j].y * acc[j].y;
    part[14] += p;
#pragma unroll
    for (int w = 0; w < 14; ++w) part[w] += ((idx >> (13 - w)) & 1) ? -p : p;
  }
  __syncthreads();
#pragma unroll
  for (int v = 0; v < 15; ++v) {
    float xv = part[v];
#pragma unroll
    for (int off = 32; off; off >>= 1) xv += __shfl_xor(xv, off);
    if ((tid & 63) == 0) red[(tid >> 6) * 15 + v] = xv;
  }
  __syncthreads();
  if (tid < 15) {
    float tot = 0.f;
#pragma unroll
    for (int w = 0; w < 8; ++w) tot += red[w * 15 + tid];
    red[128 + tid] = tot;
  }
  __syncthreads();
  if (tid < 2) {
    const float nrm = sqrtf(red[128 + 14]) + 1e-9f;
    const float iv = 1.f / (nrm * nrm);
    float o = bout[tid];
#pragma unroll
    for (int w = 0; w < 14; ++w) o += red[128 + w] * iv * Wout[w * 2 + tid];
    out[b * 2 + tid] = o;
  }
}

extern "C" void kernel_launch(void* const* d_in, const int* in_sizes, int n_in,
                              void* d_out, int out_size, void* d_ws, size_t ws_size,
                              hipStream_t stream) {
  const float* x    = (const float*)d_in[0];
  const float* Win  = (const float*)d_in[1];
  const float* bin  = (const float*)d_in[2];
  const float* mix  = (const float*)d_in[3];
  const float* poly = (const float*)d_in[4];
  const float* Wout = (const float*)d_in[5];
  const float* bout = (const float*)d_in[6];
  float* out = (float*)d_out;

  const size_t shmem = (size_t)DIM * sizeof(v2f) + 448 * sizeof(v2f) + 1024;  // 135680 B
  hipFuncSetAttribute((const void*)qts_kernel,
                      hipFuncAttributeMaxDynamicSharedMemorySize, (int)shmem);
  qts_kernel<<<256, NTH, shmem, stream>>>(x, Win, bin, mix, poly, Wout, bout, out);
}

// Round 3
// 929.591 us; speedup vs baseline: 1.8488x; 1.0063x over previous
//
#include <hip/hip_runtime.h>
#include <math.h>

#define DIM 16384
#define NTH 512

typedef float v2f __attribute__((ext_vector_type(2)));

// wire w <-> bit position (13-w). XOR bank-fold swizzle (bijective, XOR-linear).
__host__ __device__ constexpr int cswz(int i) {
  return i ^ ((i >> 4) & 15) ^ ((i >> 8) & 15) ^ ((i >> 12) & 3);
}

// local wires per pass (local bit b <-> wire LW[p][b])
constexpr int LW[8][5] = {
  {13, 12, 11, 10, 0},   // WA
  {10, 9, 8, 7, 6},      // WB
  {6, 5, 4, 3, 2},       // WC
  {2, 1, 0, 3, 4},       // WD (3,4 pad)
  {12, 13, 0, 1, 2},     // WE
  {2, 3, 4, 5, 6},       // WF
  {6, 7, 8, 9, 10},      // WG
  {10, 11, 12, 13, 9},   // WH (9 pad)
};
// tid bit k -> bit position PMAP[p][k] (permutations chosen so the 6 lane bits
// XOR-fold onto all 4 bank-pair classes -> conflict-floor gathers)
constexpr int PMAP[8][9] = {
  {4, 5, 6, 7, 8, 9, 10, 11, 12},
  {0, 1, 2, 11, 8, 9, 10, 12, 13},
  {0, 1, 2, 3, 4, 5, 6, 12, 13},
  {0, 1, 2, 3, 4, 5, 6, 7, 8},
  {2, 3, 4, 5, 6, 7, 8, 9, 10},
  {0, 1, 2, 3, 4, 5, 6, 12, 13},
  {0, 1, 2, 11, 8, 9, 10, 12, 13},
  {5, 6, 7, 8, 9, 10, 11, 12, 13},
};
constexpr int NG[8] = {9, 8, 8, 3, 9, 8, 8, 3};
// {kind(0=RY,1=CRX), bitA(RY tgt / CRX ctrl), bitB(CRX tgt), cs index (layer-rel)}
constexpr int GATES[8][9][4] = {
  {{0,4,0,0},{0,3,0,10},{0,2,0,11},{0,1,0,12},{0,0,0,13},{1,0,4,14},{1,1,0,15},{1,2,1,16},{1,3,2,17}},
  {{0,4,0,6},{0,3,0,7},{0,2,0,8},{0,1,0,9},{1,1,0,18},{1,2,1,19},{1,3,2,20},{1,4,3,21},{0,0,0,0}},
  {{0,4,0,2},{0,3,0,3},{0,2,0,4},{0,1,0,5},{1,1,0,22},{1,2,1,23},{1,3,2,24},{1,4,3,25},{0,0,0,0}},
  {{0,1,0,1},{1,1,0,26},{1,2,1,27},{0,0,0,0},{0,0,0,0},{0,0,0,0},{0,0,0,0},{0,0,0,0},{0,0,0,0}},
  {{0,2,0,28},{0,3,0,29},{0,4,0,30},{0,0,0,40},{0,1,0,41},{1,1,0,42},{1,2,1,43},{1,3,2,44},{1,4,3,45}},
  {{0,1,0,31},{0,2,0,32},{0,3,0,33},{0,4,0,34},{1,1,0,46},{1,2,1,47},{1,3,2,48},{1,4,3,49},{0,0,0,0}},
  {{0,1,0,35},{0,2,0,36},{0,3,0,37},{0,4,0,38},{1,1,0,50},{1,2,1,51},{1,3,2,52},{1,4,3,53},{0,0,0,0}},
  {{0,1,0,39},{1,1,0,54},{1,2,1,55},{0,0,0,0},{0,0,0,0},{0,0,0,0},{0,0,0,0},{0,0,0,0},{0,0,0,0}},
};

__host__ __device__ constexpr int offcube(int p, int j) {
  int o = 0;
  for (int b = 0; b < 5; ++b)
    if ((j >> b) & 1) o |= 1 << (13 - LW[p][b]);
  return o;
}

// MODE: 0 = gather+gates+scatter, 1 = |0>-init+gates+scatter, 2 = gather+gates (no scatter)
template <int PID, int MODE>
__device__ __forceinline__ void run_pass(v2f* __restrict__ S, const v2f* __restrict__ CS,
                                         int lb, int tid, v2f* __restrict__ a) {
  int base = 0;
#pragma unroll
  for (int k = 0; k < 9; ++k) base |= ((tid >> k) & 1) << PMAP[PID][k];
  const int sb = cswz(base);
  if (MODE == 1) {
#pragma unroll
    for (int j = 0; j < 32; ++j) a[j] = v2f{0.f, 0.f};
    if (tid == 0) a[0] = v2f{1.f, 0.f};
  } else {
#pragma unroll
    for (int j = 0; j < 32; ++j) a[j] = S[sb ^ cswz(offcube(PID, j))];
  }
#pragma unroll
  for (int g = 0; g < NG[PID]; ++g) {
    const v2f cs2 = CS[lb + GATES[PID][g][3]];
    const float c = cs2.x, s = cs2.y;
    if (GATES[PID][g][0] == 0) {
      const int tb = GATES[PID][g][1];
#pragma unroll
      for (int j = 0; j < 32; ++j)
        if (!((j >> tb) & 1)) {
          const int j2 = j | (1 << tb);
          const v2f a0 = a[j], a1 = a[j2];
          a[j]  = c * a0 - s * a1;
          a[j2] = s * a0 + c * a1;
        }
    } else {
      const int bc = GATES[PID][g][1], bt = GATES[PID][g][2];
#pragma unroll
      for (int j = 0; j < 32; ++j)
        if (((j >> bc) & 1) && !((j >> bt) & 1)) {
          const int j2 = j | (1 << bt);
          const v2f t0 = a[j], t1 = a[j2];
          a[j]  = c * t0 + s * v2f{t1.y, -t1.x};
          a[j2] = c * t1 + s * v2f{t0.y, -t0.x};
        }
    }
  }
  if (MODE != 2) {
#pragma unroll
    for (int j = 0; j < 32; ++j) S[sb ^ cswz(offcube(PID, j))] = a[j];
  }
  __syncthreads();
}

// one full 112-gate sim; a[] ends holding the final state in the WH cube mapping
__device__ __forceinline__ void run_sim(v2f* __restrict__ S, const v2f* __restrict__ CS,
                                        int tid, v2f* __restrict__ a,
                                        const v2f* __restrict__ basev, int own_sb,
                                        bool initzero) {
  if (initzero) {
    run_pass<0, 1>(S, CS, 0, tid, a);
  } else {
#pragma unroll
    for (int j = 0; j < 32; ++j) S[own_sb ^ cswz(offcube(7, j))] = basev[j];
    __syncthreads();
    run_pass<0, 0>(S, CS, 0, tid, a);
  }
  run_pass<1, 0>(S, CS, 0, tid, a);
  run_pass<2, 0>(S, CS, 0, tid, a);
  run_pass<3, 0>(S, CS, 0, tid, a);
  run_pass<4, 0>(S, CS, 0, tid, a);
  run_pass<5, 0>(S, CS, 0, tid, a);
  run_pass<6, 0>(S, CS, 0, tid, a);
  run_pass<7, 0>(S, CS, 0, tid, a);
  run_pass<0, 0>(S, CS, 56, tid, a);
  run_pass<1, 0>(S, CS, 56, tid, a);
  run_pass<2, 0>(S, CS, 56, tid, a);
  run_pass<3, 0>(S, CS, 56, tid, a);
  run_pass<4, 0>(S, CS, 56, tid, a);
  run_pass<5, 0>(S, CS, 56, tid, a);
  run_pass<6, 0>(S, CS, 56, tid, a);
  run_pass<7, 2>(S, CS, 56, tid, a);  // final: keep in registers
}

__device__ __forceinline__ float block_sum(float v, int tid, float* red) {
#pragma unroll
  for (int off = 32; off; off >>= 1) v += __shfl_xor(v, off);
  if ((tid & 63) == 0) red[tid >> 6] = v;
  __syncthreads();
  float tot = 0.f;
#pragma unroll
  for (int w = 0; w < 8; ++w) tot += red[w];
  __syncthreads();
  return tot;
}

__global__ __launch_bounds__(NTH, 1) void qts_kernel(
    const float* __restrict__ x, const float* __restrict__ Win,
    const float* __restrict__ bin, const float* __restrict__ mix,
    const float* __restrict__ poly, const float* __restrict__ Wout,
    const float* __restrict__ bout, float* __restrict__ out) {
  extern __shared__ v2f S[];           // DIM state + 448 cos/sin + reduce scratch
  v2f* CSall = S + DIM;
  float* red = (float*)(S + DIM + 448);
  const int tid = threadIdx.x;
  const int b = blockIdx.x;

  // angles for all 4 timesteps at once: theta = sigmoid(x@Win+bin); store (cos,sin)(theta/2)
  if (tid < 448) {
    float z = bin[tid];
    const float x0 = x[b * 4 + 0], x1 = x[b * 4 + 1], x2 = x[b * 4 + 2], x3 = x[b * 4 + 3];
    z += x0 * Win[tid] + x1 * Win[448 + tid] + x2 * Win[896 + tid] + x3 * Win[1344 + tid];
    const float th = 1.f / (1.f + expf(-z));
    float sn, cc;
    sincosf(0.5f * th, &sn, &cc);
    CSall[tid] = v2f{cc, sn};
  }
  __syncthreads();

  int ownbase = 0;
#pragma unroll
  for (int k = 0; k < 9; ++k) ownbase |= ((tid >> k) & 1) << PMAP[7][k];
  const int own_sb = cswz(ownbase);

  const float mixv[4] = {mix[0], mix[1], mix[2], mix[3]};
  const float p0 = poly[0], p1 = poly[1], p2 = poly[2];

  v2f a[32], acc[32], basev[32];
  float alpha;

  // ---- degree 0 (base = |0>) ----
#pragma unroll
  for (int j = 0; j < 32; ++j) acc[j] = v2f{0.f, 0.f};
  for (int t = 0; t < 4; ++t) {
    run_sim(S, CSall + t * 112, tid, a, basev, own_sb, true);
    const float mc = mixv[t];
#pragma unroll
    for (int j = 0; j < 32; ++j) acc[j] += mc * a[j];
  }
  {
    float part = 0.f;
#pragma unroll
    for (int j = 0; j < 32; ++j) part += acc[j].x * acc[j].x + acc[j].y * acc[j].y;
    const float tot = block_sum(part, tid, red);
    const float nu = sqrtf(tot) + 1e-9f;
    const float inv = 1.f / nu;
    alpha = p0 * nu;                   // res-so-far == alpha * basev
#pragma unroll
    for (int j = 0; j < 32; ++j) { basev[j] = inv * acc[j]; acc[j] = v2f{0.f, 0.f}; }
  }

  // ---- degree 1 ----
  for (int t = 0; t < 4; ++t) {
    run_sim(S, CSall + t * 112, tid, a, basev, own_sb, false);
    const float mc = mixv[t];
#pragma unroll
    for (int j = 0; j < 32; ++j) acc[j] += mc * a[j];
  }
  {
    float part = 0.f;
#pragma unroll
    for (int j = 0; j < 32; ++j) part += acc[j].x * acc[j].x + acc[j].y * acc[j].y;
    const float tot = block_sum(part, tid, red);
    const float nu = sqrtf(tot) + 1e-9f;
    const float inv = 1.f / nu;
#pragma unroll
    for (int j = 0; j < 32; ++j) {
      const v2f tmp = acc[j];
      acc[j] = alpha * basev[j] + p1 * tmp;  // acc becomes res accumulator
      basev[j] = inv * tmp;
    }
  }

  // ---- degree 2 (accumulate straight into res) ----
  for (int t = 0; t < 4; ++t) {
    run_sim(S, CSall + t * 112, tid, a, basev, own_sb, false);
    const float mc = p2 * mixv[t];
#pragma unroll
    for (int j = 0; j < 32; ++j) acc[j] += mc * a[j];
  }

  // ---- expz per wire + total norm from res (= acc), then tiny GEMV ----
  float part[15];
#pragma unroll
  for (int v = 0; v < 15; ++v) part[v] = 0.f;
#pragma unroll
  for (int j = 0; j < 32; ++j) {
    const int idx = ownbase | offcube(7, j);
    const float p = acc[j].x * acc[j].x + acc[j].y * acc[j].y;
    part[14] += p;
#pragma unroll
    for (int w = 0; w < 14; ++w) part[w] += ((idx >> (13 - w)) & 1) ? -p : p;
  }
  __syncthreads();
#pragma unroll
  for (int v = 0; v < 15; ++v) {
    float xv = part[v];
#pragma unroll
    for (int off = 32; off; off >>= 1) xv += __shfl_xor(xv, off);
    if ((tid & 63) == 0) red[(tid >> 6) * 15 + v] = xv;
  }
  __syncthreads();
  if (tid < 15) {
    float tot = 0.f;
#pragma unroll
    for (int w = 0; w < 8; ++w) tot += red[w * 15 + tid];
    red[128 + tid] = tot;
  }
  __syncthreads();
  if (tid < 2) {
    const float nrm = sqrtf(red[128 + 14]) + 1e-9f;
    const float iv = 1.f / (nrm * nrm);
    float o = bout[tid];
#pragma unroll
    for (int w = 0; w < 14; ++w) o += red[128 + w] * iv * Wout[w * 2 + tid];
    out[b * 2 + tid] = o;
  }
}

extern "C" void kernel_launch(void* const* d_in, const int* in_sizes, int n_in,
                              void* d_out, int out_size, void* d_ws, size_t ws_size,
                              hipStream_t stream) {
  const float* x    = (const float*)d_in[0];
  const float* Win  = (const float*)d_in[1];
  const float* bin  = (const float*)d_in[2];
  const float* mix  = (const float*)d_in[3];
  const float* poly = (const float*)d_in[4];
  const float* Wout = (const float*)d_in[5];
  const float* bout = (const float*)d_in[6];
  float* out = (float*)d_out;

  const size_t shmem = (size_t)DIM * sizeof(v2f) + 448 * sizeof(v2f) + 1024;  // 135680 B
  hipFuncSetAttribute((const void*)qts_kernel,
                      hipFuncAttributeMaxDynamicSharedMemorySize, (int)shmem);
  qts_kernel<<<256, NTH, shmem, stream>>>(x, Win, bin, mix, poly, Wout, bout, out);
}